// Round 10
// baseline (234.519 us; speedup 1.0000x reference)
//
#include <hip/hip_runtime.h>
#include <hip/hip_bf16.h>

typedef short short8 __attribute__((ext_vector_type(8)));
typedef float f32x4 __attribute__((ext_vector_type(4)));

#define M_TOT 16384   // B*S = 4*4096
#define NDIM  1024    // D = U = 1024
#define BK 32
#define NT (NDIM / BK)   // 32 K-tiles

static __device__ __forceinline__ unsigned short f2bf(float f) {
  unsigned int u = __builtin_bit_cast(unsigned int, f);
  unsigned int r = (u + 0x7fffu + ((u >> 16) & 1u)) >> 16;   // RN-even
  return (unsigned short)r;
}
static __device__ __forceinline__ float bf2f(unsigned short u) {
  return __builtin_bit_cast(float, ((unsigned int)u) << 16);
}

// compile-time-only reorder fence (zero runtime cost)
#define CLB() asm volatile("" ::: "memory")
#define VMW(N) asm volatile("s_waitcnt vmcnt(" #N ")" ::: "memory")
#define BAR() do { CLB(); __builtin_amdgcn_s_barrier(); CLB(); } while (0)

// ---------------- cast inputs fp32 -> bf16, vectorized ----------------
__global__ __launch_bounds__(256) void cast_in(const float* __restrict__ in,
                                               unsigned short* __restrict__ out,
                                               int n4) {
  int i = blockIdx.x * 256 + threadIdx.x;
  if (i >= n4) return;
  float4 v = reinterpret_cast<const float4*>(in)[i];
  ushort4 o;
  o.x = f2bf(v.x); o.y = f2bf(v.y); o.z = f2bf(v.z); o.w = f2bf(v.w);
  reinterpret_cast<ushort4*>(out)[i] = o;
}

// ---- transpose-cast 4 weights fp32 [K][N] -> bf16 [N][K], one launch ----
__global__ __launch_bounds__(256) void tcast4(
    const float* __restrict__ w1, const float* __restrict__ w2,
    const float* __restrict__ wg, const float* __restrict__ ws,
    unsigned short* __restrict__ W1t, unsigned short* __restrict__ W2t,
    unsigned short* __restrict__ Wgt, unsigned short* __restrict__ Wst) {
  const int z = blockIdx.z;
  const float* src = (z == 0) ? w1 : (z == 1) ? w2 : (z == 2) ? wg : ws;
  unsigned short* dst = (z == 0) ? W1t : (z == 1) ? W2t : (z == 2) ? Wgt : Wst;
  __shared__ unsigned short tile[32][33];
  int bx = blockIdx.x * 32, by = blockIdx.y * 32;
  int x = threadIdx.x & 31, y = threadIdx.x >> 5;  // 32 x 8
#pragma unroll
  for (int i = 0; i < 32; i += 8)
    tile[y + i][x] = f2bf(src[(size_t)(by + y + i) * NDIM + bx + x]);
  __syncthreads();
#pragma unroll
  for (int i = 0; i < 32; i += 8)
    dst[(size_t)(bx + y + i) * NDIM + by + x] = tile[x][y + i];
}

// ========== tri-GEMM v2: 256x128 tile, 8 waves, stage A once (r9) ==========
// H = bf16(relu(x@W1+b1)); G = bf16(sigmoid(x@Wg+bg)); S = bf16(x@Ws+bs)
__global__ __launch_bounds__(512, 2) void trigemm(
    const unsigned short* __restrict__ A,
    const unsigned short* __restrict__ W1t,
    const unsigned short* __restrict__ Wgt,
    const unsigned short* __restrict__ Wst,
    const float* __restrict__ b1,
    const float* __restrict__ bg,
    const float* __restrict__ bs,
    unsigned short* __restrict__ H,
    unsigned short* __restrict__ G,
    unsigned short* __restrict__ S) {
  // per buf: shorts 0..8191 = A (row-major 256x32), 8192 + w*4096 + row*32 = W_w
  __shared__ __align__(16) unsigned short lds[2][20480];  // 80 KB

  const int tid = threadIdx.x;
  const int lane = tid & 63;
  const int wave = tid >> 6;            // 0..7
  const int wm = wave >> 1;             // 0..3  (64-row band)
  const int wn = wave & 1;              // 0..1  (64-col half)
  const int lr = lane & 15;
  const int lk = lane >> 4;

  // XCD swizzle: 8 col-blocks sharing an A row-panel -> same XCD.
  const int id = blockIdx.x;
  const int xcd = id & 7;
  const int slot = id >> 3;                // 0..63
  const int rblk = xcd + 8 * (slot >> 3);  // 0..63
  const int cblk = slot & 7;               // 0..7
  const int m0 = rblk * 256, n0 = cblk * 128;

  const unsigned short* gA = A + (size_t)m0 * NDIM;
  const unsigned short* gW[3] = {W1t + (size_t)n0 * NDIM, Wgt + (size_t)n0 * NDIM,
                                 Wst + (size_t)n0 * NDIM};

  f32x4 acc[3][4][4] = {};

  // stage K-tile kt: A 1024 chunks + 3x512 W chunks = 2560 / 512thr = 5 each
  auto stage = [&](int buf, int kt) {
#pragma unroll
    for (int q = 0; q < 5; ++q) {
      int cid = q * 512 + tid;             // 0..2559
      const unsigned short* g;
      if (q < 2) {                          // A chunks 0..1023
        int row = cid >> 2;                 // 0..255
        int c = (cid & 3) ^ ((row >> 1) & 3);
        g = gA + (size_t)row * NDIM + kt * BK + c * 8;
      } else {                              // W chunks, mat = q-2 (compile-time)
        int local = cid - 1024;
        int w = q - 2;
        int lrow = local & 511;
        int row = lrow >> 2;                // 0..127
        int c = (lrow & 3) ^ ((row >> 1) & 3);
        g = gW[w] + (size_t)row * NDIM + kt * BK + c * 8;
      }
      unsigned short* l = &lds[buf][0] + (size_t)(q * 512 + (tid & ~63)) * 8;
      __builtin_amdgcn_global_load_lds(
          (__attribute__((address_space(1))) void*)g,
          (__attribute__((address_space(3))) void*)l, 16, 0, 0);
    }
  };

  auto compute = [&](int buf) {
    short8 af[4];
#pragma unroll
    for (int mi = 0; mi < 4; ++mi) {
      int row = wm * 64 + mi * 16 + lr;
      int cs = lk ^ ((row >> 1) & 3);
      af[mi] = *reinterpret_cast<const short8*>(&lds[buf][row * 32 + cs * 8]);
    }
#pragma unroll
    for (int w = 0; w < 3; ++w) {
      short8 bf[4];
#pragma unroll
      for (int nj = 0; nj < 4; ++nj) {
        int row = wn * 64 + nj * 16 + lr;
        int cs = lk ^ ((row >> 1) & 3);
        bf[nj] = *reinterpret_cast<const short8*>(
            &lds[buf][8192 + w * 4096 + row * 32 + cs * 8]);
      }
      __builtin_amdgcn_s_setprio(1);
#pragma unroll
      for (int mi = 0; mi < 4; ++mi)
#pragma unroll
        for (int nj = 0; nj < 4; ++nj)
          acc[w][mi][nj] = __builtin_amdgcn_mfma_f32_16x16x32_bf16(
              af[mi], bf[nj], acc[w][mi][nj], 0, 0, 0);
      __builtin_amdgcn_s_setprio(0);
    }
  };

  stage(0, 0);
  for (int t = 0; t < NT; ++t) {
    const int cur = t & 1;
    if (t + 1 < NT) {
      stage(cur ^ 1, t + 1);   // 5 new in flight, then wait current 5
      VMW(5);
    } else {
      VMW(0);
    }
    BAR();
    compute(cur);
    BAR();
  }

  // epilogue: C/D layout col = lane&15, row = (lane>>4)*4 + r
  const int crow0 = m0 + wm * 64;
  const int ccol0 = n0 + wn * 64;
#pragma unroll
  for (int w = 0; w < 3; ++w) {
    const float* bptr = (w == 0) ? b1 : (w == 1) ? bg : bs;
    unsigned short* optr = (w == 0) ? H : (w == 1) ? G : S;
#pragma unroll
    for (int mi = 0; mi < 4; ++mi) {
#pragma unroll
      for (int nj = 0; nj < 4; ++nj) {
        int row = crow0 + mi * 16 + (lk << 2);
        int col = ccol0 + nj * 16 + lr;
        float bc = bptr[col];
#pragma unroll
        for (int r = 0; r < 4; ++r) {
          float v = acc[w][mi][nj][r] + bc;
          if (w == 0) v = fmaxf(v, 0.f);
          else if (w == 1) v = 1.f / (1.f + __expf(-v));
          optr[(size_t)(row + r) * NDIM + col] = f2bf(v);
        }
      }
    }
  }
}

// ====== fused GEMM-2 + gate + skip + LayerNorm (LDS-staged W2) ======
// Out = LN( (H@W2^T + b2)*G + S ) * gamma + beta   (fp32)
// Block = 64 rows x ALL 1024 cols (full rows -> LN fuses in-register).
// 8 waves x 128 cols; BK=32; W2 k-slice 1024x32 (64KB) double-buffered in
// LDS via the proven staging (8 gload_lds/thr, same swizzle, counted VMW(8),
// 2 barriers/tile).  H fragments: 4 plain global b128 loads/wave/tile —
// all waves read the SAME 64 H-rows (L1-broadcast, L2-hot from trigemm).
// acc[4][8]=128 VGPR + frags ~ 230 < 256 @ 2 waves/SIMD -> no spill.
__global__ __launch_bounds__(512, 2) void gemm_y_ln(
    const unsigned short* __restrict__ H,
    const unsigned short* __restrict__ W2t,
    const float* __restrict__ b2,
    const unsigned short* __restrict__ G,
    const unsigned short* __restrict__ S,
    const float* __restrict__ gamma,
    const float* __restrict__ beta,
    float* __restrict__ Out) {
  __shared__ __align__(16) unsigned short Bs[2][1024][BK];  // 128 KB
  __shared__ float redS[8][64];
  __shared__ float redQ[8][64];
  __shared__ float2 fin[64];

  const int tid = threadIdx.x;
  const int lane = tid & 63;
  const int wave = tid >> 6;        // 0..7 -> 128-col slice
  const int m0 = blockIdx.x * 64;
  const int c0 = wave * 128;
  const int lr = lane & 15;         // row (A) / col (B) within fragment
  const int lk = lane >> 4;         // k-chunk 0..3 (8 bf16 each)

  const unsigned short* aBase = H + (size_t)(m0 + lr) * NDIM + lk * 8;

  f32x4 acc[4][8] = {};

  // stage one K-slice of W2t (1024 rows x 32 k = 4096 chunks): 8 per thread
  auto stage = [&](int buf, int kt) {
#pragma unroll
    for (int q = 0; q < 8; ++q) {
      int cid = q * 512 + tid;                 // 0..4095
      int row = cid >> 2;                      // 0..1023
      int c = (cid & 3) ^ ((row >> 1) & 3);    // pre-swizzled global k-chunk
      const unsigned short* g = W2t + (size_t)row * NDIM + kt * BK + c * 8;
      unsigned short* l = &Bs[buf][0][0] + (size_t)(q * 512 + (tid & ~63)) * 8;
      __builtin_amdgcn_global_load_lds(
          (__attribute__((address_space(1))) void*)g,
          (__attribute__((address_space(3))) void*)l, 16, 0, 0);
    }
  };

  auto compute = [&](int buf, int kt) {
    short8 af[4], bf[8];
#pragma unroll
    for (int mi = 0; mi < 4; ++mi)
      af[mi] = *reinterpret_cast<const short8*>(
          aBase + (size_t)mi * 16 * NDIM + kt * BK);
#pragma unroll
    for (int nj = 0; nj < 8; ++nj) {
      int row = c0 + nj * 16 + lr;
      int cs = lk ^ ((row >> 1) & 3);
      bf[nj] = *reinterpret_cast<const short8*>(&Bs[buf][row][cs * 8]);
    }
    __builtin_amdgcn_s_setprio(1);
#pragma unroll
    for (int mi = 0; mi < 4; ++mi)
#pragma unroll
      for (int nj = 0; nj < 8; ++nj)
        acc[mi][nj] = __builtin_amdgcn_mfma_f32_16x16x32_bf16(
            af[mi], bf[nj], acc[mi][nj], 0, 0, 0);
    __builtin_amdgcn_s_setprio(0);
  };

  stage(0, 0);
  for (int t = 0; t < NT; ++t) {
    const int cur = t & 1;
    if (t + 1 < NT) {
      stage(cur ^ 1, t + 1);
      VMW(8);                 // tile t landed; t+1's 8 stay in flight
    } else {
      VMW(0);
    }
    BAR();
    compute(cur, t);
    BAR();
  }

  // ---- epilogue: bias, gate, skip (fp32), per-row partial sums ----
  float s1[4][4], s2[4][4];
#pragma unroll
  for (int mi = 0; mi < 4; ++mi) {
#pragma unroll
    for (int r = 0; r < 4; ++r) {
      int row = m0 + mi * 16 + lk * 4 + r;
      float rs1 = 0.f, rs2 = 0.f;
#pragma unroll
      for (int nj = 0; nj < 8; ++nj) {
        int col = c0 + nj * 16 + lr;
        size_t idx = (size_t)row * NDIM + col;
        float v = acc[mi][nj][r] + b2[col];
        v = v * bf2f(G[idx]) + bf2f(S[idx]);
        acc[mi][nj][r] = v;
        rs1 += v; rs2 += v * v;
      }
      s1[mi][r] = rs1; s2[mi][r] = rs2;
    }
  }

  // reduce across the 16 lanes (lr) sharing the same rows
#pragma unroll
  for (int off = 1; off < 16; off <<= 1) {
#pragma unroll
    for (int mi = 0; mi < 4; ++mi)
#pragma unroll
      for (int r = 0; r < 4; ++r) {
        s1[mi][r] += __shfl_xor(s1[mi][r], off, 16);
        s2[mi][r] += __shfl_xor(s2[mi][r], off, 16);
      }
  }

  // cross-wave reduce (8 waves -> full 1024 cols) via tiny LDS
  if (lr == 0) {
#pragma unroll
    for (int mi = 0; mi < 4; ++mi)
#pragma unroll
      for (int r = 0; r < 4; ++r) {
        int rl = mi * 16 + lk * 4 + r;
        redS[wave][rl] = s1[mi][r];
        redQ[wave][rl] = s2[mi][r];
      }
  }
  __syncthreads();
  if (tid < 64) {
    float a1 = 0.f, a2 = 0.f;
#pragma unroll
    for (int w = 0; w < 8; ++w) { a1 += redS[w][tid]; a2 += redQ[w][tid]; }
    float mu = a1 * (1.f / NDIM);
    float var = a2 * (1.f / NDIM) - mu * mu;
    fin[tid] = make_float2(mu, rsqrtf(var + 1e-3f));
  }
  __syncthreads();

  // normalize + write fp32 (gamma/beta loaded here, after s1/s2 die)
#pragma unroll
  for (int mi = 0; mi < 4; ++mi) {
#pragma unroll
    for (int r = 0; r < 4; ++r) {
      int rl = mi * 16 + lk * 4 + r;
      float2 f = fin[rl];
      float* orow = Out + (size_t)(m0 + rl) * NDIM;
#pragma unroll
      for (int nj = 0; nj < 8; ++nj) {
        int col = c0 + nj * 16 + lr;
        orow[col] = (acc[mi][nj][r] - f.x) * f.y * gamma[col] + beta[col];
      }
    }
  }
}

extern "C" void kernel_launch(void* const* d_in, const int* in_sizes, int n_in,
                              void* d_out, int out_size, void* d_ws, size_t ws_size,
                              hipStream_t stream) {
  const float* inp = (const float*)d_in[0];
  const float* w1 = (const float*)d_in[1];
  const float* b1 = (const float*)d_in[2];
  const float* w2 = (const float*)d_in[3];
  const float* b2 = (const float*)d_in[4];
  const float* wg = (const float*)d_in[5];
  const float* bg = (const float*)d_in[6];
  const float* wsk = (const float*)d_in[7];
  const float* bs = (const float*)d_in[8];
  const float* gamma = (const float*)d_in[9];
  const float* beta = (const float*)d_in[10];

  char* p = (char*)d_ws;
  const size_t act_bf16 = (size_t)M_TOT * NDIM * 2;
  const size_t w_bf16 = (size_t)NDIM * NDIM * 2;
  unsigned short* Ain = (unsigned short*)p; p += act_bf16;
  unsigned short* H   = (unsigned short*)p; p += act_bf16;
  unsigned short* G   = (unsigned short*)p; p += act_bf16;
  unsigned short* S   = (unsigned short*)p; p += act_bf16;
  unsigned short* W1t = (unsigned short*)p; p += w_bf16;
  unsigned short* W2t = (unsigned short*)p; p += w_bf16;
  unsigned short* Wgt = (unsigned short*)p; p += w_bf16;
  unsigned short* Wst = (unsigned short*)p; p += w_bf16;

  cast_in<<<(M_TOT * NDIM / 4 + 255) / 256, 256, 0, stream>>>(inp, Ain, M_TOT * NDIM / 4);
  tcast4<<<dim3(32, 32, 4), 256, 0, stream>>>(w1, w2, wg, wsk, W1t, W2t, Wgt, Wst);

  trigemm<<<(M_TOT / 256) * (NDIM / 128), 512, 0, stream>>>(
      Ain, W1t, Wgt, Wst, b1, bg, bs, H, G, S);
  gemm_y_ln<<<M_TOT / 64, 512, 0, stream>>>(H, W2t, b2, G, S, gamma, beta,
                                            (float*)d_out);
}

// Round 11
// 218.885 us; speedup vs baseline: 1.0714x; 1.0714x over previous
//
#include <hip/hip_runtime.h>
#include <hip/hip_bf16.h>

typedef short short8 __attribute__((ext_vector_type(8)));
typedef float f32x4 __attribute__((ext_vector_type(4)));

#define M_TOT 16384   // B*S = 4*4096
#define NDIM  1024    // D = U = 1024
#define BK 64         // K-step per tile
#define NI (NDIM / (2 * BK))   // 8 iterations, 2 K-tiles each

static __device__ __forceinline__ unsigned short f2bf(float f) {
  unsigned int u = __builtin_bit_cast(unsigned int, f);
  unsigned int r = (u + 0x7fffu + ((u >> 16) & 1u)) >> 16;   // RN-even
  return (unsigned short)r;
}
static __device__ __forceinline__ float bf2f(unsigned short u) {
  return __builtin_bit_cast(float, ((unsigned int)u) << 16);
}

#define CLB() asm volatile("" ::: "memory")
#define VMW(N) asm volatile("s_waitcnt vmcnt(" #N ")" ::: "memory")
#define LGKM0() asm volatile("s_waitcnt lgkmcnt(0)" ::: "memory")
#define BAR() do { CLB(); __builtin_amdgcn_s_barrier(); CLB(); } while (0)

// ---------------- cast inputs fp32 -> bf16, vectorized ----------------
__global__ __launch_bounds__(256) void cast_in(const float* __restrict__ in,
                                               unsigned short* __restrict__ out,
                                               int n4) {
  int i = blockIdx.x * 256 + threadIdx.x;
  if (i >= n4) return;
  float4 v = reinterpret_cast<const float4*>(in)[i];
  ushort4 o;
  o.x = f2bf(v.x); o.y = f2bf(v.y); o.z = f2bf(v.z); o.w = f2bf(v.w);
  reinterpret_cast<ushort4*>(out)[i] = o;
}

// ---- transpose-cast 4 weights fp32 [K][N] -> bf16 [N][K], one launch ----
__global__ __launch_bounds__(256) void tcast4(
    const float* __restrict__ w1, const float* __restrict__ w2,
    const float* __restrict__ wg, const float* __restrict__ ws,
    unsigned short* __restrict__ W1t, unsigned short* __restrict__ W2t,
    unsigned short* __restrict__ Wgt, unsigned short* __restrict__ Wst) {
  const int z = blockIdx.z;
  const float* src = (z == 0) ? w1 : (z == 1) ? w2 : (z == 2) ? wg : ws;
  unsigned short* dst = (z == 0) ? W1t : (z == 1) ? W2t : (z == 2) ? Wgt : Wst;
  __shared__ unsigned short tile[32][33];
  int bx = blockIdx.x * 32, by = blockIdx.y * 32;
  int x = threadIdx.x & 31, y = threadIdx.x >> 5;  // 32 x 8
#pragma unroll
  for (int i = 0; i < 32; i += 8)
    tile[y + i][x] = f2bf(src[(size_t)(by + y + i) * NDIM + bx + x]);
  __syncthreads();
#pragma unroll
  for (int i = 0; i < 32; i += 8)
    dst[(size_t)(bx + y + i) * NDIM + by + x] = tile[x][y + i];
}

// ============ m201-style 8-phase 256x256 / BK=64 bf16 MFMA GEMM ============
// C = A[M][K] * Bt[N][K]^T, K = NDIM.  8 waves (2M x 4N), 128x64 per wave.
// MODE 0: O = bf16(relu(C+bias))      MODE 1: O = bf16(sigmoid(C+bias))
// MODE 2: O = bf16(C+bias)            MODE 3: O = bf16((C+bias)*G + S)
//
// LDS [slot2][mat2][half2][128 rows][64 k] bf16 = 128 KiB.  Half-tile =
// 128 rows x 64 k = 16 KB = 2 gload_lds x 512 thr.  Swizzle: stored chunk
// kcs holds global chunk kcs ^ (row&7) -> every ds_read_b128 is exactly
// 2 lanes/bank (free).  Per iteration (tiles e=2t in slot0, o=2t+1 in
// slot1), 8 phases; stage schedule (derived + race-checked):
//   P1: odd.A0<-o   P2: odd.A1<-o   P3: even.B0<-e+2  P4: even.B1<-e+2,VMW(4)
//   P5: even.A0<-e+2 P6: even.A1<-e+2 P7: odd.B0<-o+2 P8: odd.B1<-o+2,VMW(4)
// Each half overwritten >=1 phase after its last LDS read (end-barrier
// ordered); each drained by the VMW before its first read.  vmcnt never 0
// mid-loop (T4); setprio around each 16-MFMA cluster (T5).
template <int MODE>
__global__ __launch_bounds__(512, 2) void gemm8p(
    const unsigned short* __restrict__ A,
    const unsigned short* __restrict__ Bt,
    const float* __restrict__ bias,
    unsigned short* __restrict__ O,
    const unsigned short* __restrict__ G,
    const unsigned short* __restrict__ S) {
  __shared__ __align__(16) unsigned short lds[2][2][2][128][64];  // 128 KB

  const int tid = threadIdx.x;
  const int lane = tid & 63;
  const int wave = tid >> 6;        // 0..7
  const int wm = wave >> 2;         // 0..1  (128-row half)
  const int wn = wave & 3;          // 0..3  (64-col quarter)
  const int lr = lane & 15;
  const int lk = lane >> 4;

  // XCD swizzle: 4 col-blocks sharing an A row-panel -> same XCD (256 blocks)
  const int id = blockIdx.x;
  const int xcd = id & 7;
  const int slot = id >> 3;                 // 0..31
  const int rblk = xcd + 8 * (slot >> 2);   // 0..63
  const int cblk = slot & 3;                // 0..3
  const int m0 = rblk * 256, n0 = cblk * 256;

  const unsigned short* gA = A + (size_t)m0 * NDIM;
  const unsigned short* gB = Bt + (size_t)n0 * NDIM;

  f32x4 acc[8][4] = {};

  // stage one half-tile (s=slot, mat 0=A/1=B, h=row-half) of K-tile kt
  auto stage = [&](int s, int mat, int h, int kt) {
    const unsigned short* gb =
        (mat ? gB : gA) + (size_t)(h * 128) * NDIM + kt * BK;
    unsigned short* lb = &lds[s][mat][h][0][0];
#pragma unroll
    for (int q = 0; q < 2; ++q) {
      int c = q * 512 + tid;             // 16B chunk 0..1023
      int row = c >> 3;
      int kc = (c & 7) ^ (row & 7);      // pre-swizzled global chunk
      const unsigned short* g = gb + (size_t)row * NDIM + kc * 8;
      unsigned short* l = lb + (size_t)(q * 512 + (tid & ~63)) * 8;
      __builtin_amdgcn_global_load_lds(
          (__attribute__((address_space(1))) void*)g,
          (__attribute__((address_space(3))) void*)l, 16, 0, 0);
    }
  };

  // fragment readers: d[idx*2+kk]; A: 4 mi-rows of one mih; B: 2 nj of one njh
  auto ldA = [&](short8* d, int s, int mih) {
#pragma unroll
    for (int mi = 0; mi < 4; ++mi)
#pragma unroll
      for (int kk = 0; kk < 2; ++kk) {
        int lrow = (mih * 4 + mi) * 16 + lr;
        int kc = (kk * 4 + lk) ^ (lr & 7);
        d[mi * 2 + kk] =
            *reinterpret_cast<const short8*>(&lds[s][0][wm][lrow][kc * 8]);
      }
  };
  auto ldB = [&](short8* d, int s, int njh) {
#pragma unroll
    for (int nj = 0; nj < 2; ++nj)
#pragma unroll
      for (int kk = 0; kk < 2; ++kk) {
        int lrow = (wn & 1) * 64 + (njh * 2 + nj) * 16 + lr;
        int kc = (kk * 4 + lk) ^ (lr & 7);
        d[nj * 2 + kk] = *reinterpret_cast<const short8*>(
            &lds[s][1][wn >> 1][lrow][kc * 8]);
      }
  };

#define QUAD(AF, BF, MI0, NJ0)                                              \
  do {                                                                     \
    __builtin_amdgcn_s_setprio(1);                                         \
    _Pragma("unroll") for (int kk = 0; kk < 2; ++kk)                       \
    _Pragma("unroll") for (int mi = 0; mi < 4; ++mi)                       \
    _Pragma("unroll") for (int nj = 0; nj < 2; ++nj)                       \
      acc[MI0 + mi][NJ0 + nj] = __builtin_amdgcn_mfma_f32_16x16x32_bf16(   \
          AF[mi * 2 + kk], BF[nj * 2 + kk], acc[MI0 + mi][NJ0 + nj], 0, 0, 0); \
    __builtin_amdgcn_s_setprio(0);                                         \
  } while (0)

  // ---- prologue: tile 0 (even slot, all 4 halves) + tile 1 B-halves ----
  stage(0, 1, 0, 0);   // even.B0
  stage(0, 1, 1, 0);   // even.B1
  stage(0, 0, 0, 0);   // even.A0
  stage(0, 0, 1, 0);   // even.A1
  stage(1, 1, 0, 1);   // odd.B0
  stage(1, 1, 1, 1);   // odd.B1
  VMW(4);              // drain tile 0; odd.B0/B1 stay in flight
  BAR();

  short8 aF[8], b01[4], b23[4];

  for (int t = 0; t < NI; ++t) {
    const bool more = (t + 1 < NI);
    const int te = 2 * t + 2;   // next even tile
    const int to = 2 * t + 3;   // next odd tile

    // ---- P1: stage odd.A0 (tile 2t+1); read A(mih0)+B(njh0) of even ----
    stage(1, 0, 0, 2 * t + 1);
    ldA(aF, 0, 0);
    ldB(b01, 0, 0);
    BAR(); LGKM0();
    QUAD(aF, b01, 0, 0);
    BAR();

    // ---- P2: stage odd.A1; read B(njh1) of even ----
    stage(1, 0, 1, 2 * t + 1);
    ldB(b23, 0, 1);
    BAR(); LGKM0();
    QUAD(aF, b23, 0, 2);
    BAR();

    // ---- P3: stage even.B0 (tile 2t+2); read A(mih1) of even ----
    if (more) stage(0, 1, 0, te);
    ldA(aF, 0, 1);
    BAR(); LGKM0();
    QUAD(aF, b23, 4, 2);
    BAR();

    // ---- P4: stage even.B1; no reads; vmcnt ----
    if (more) stage(0, 1, 1, te);
    BAR();
    QUAD(aF, b01, 4, 0);
    if (more) { VMW(4); } else { VMW(0); }
    BAR();

    // ---- P5: stage even.A0; read A(mih0)+B(njh0) of odd ----
    if (more) stage(0, 0, 0, te);
    ldA(aF, 1, 0);
    ldB(b01, 1, 0);
    BAR(); LGKM0();
    QUAD(aF, b01, 0, 0);
    BAR();

    // ---- P6: stage even.A1; read B(njh1) of odd ----
    if (more) stage(0, 0, 1, te);
    ldB(b23, 1, 1);
    BAR(); LGKM0();
    QUAD(aF, b23, 0, 2);
    BAR();

    // ---- P7: stage odd.B0 (tile 2t+3); read A(mih1) of odd ----
    if (more) stage(1, 1, 0, to);
    ldA(aF, 1, 1);
    BAR(); LGKM0();
    QUAD(aF, b23, 4, 2);
    BAR();

    // ---- P8: stage odd.B1; no reads; vmcnt ----
    if (more) stage(1, 1, 1, to);
    BAR();
    QUAD(aF, b01, 4, 0);
    if (more) VMW(4);
    BAR();
  }

  // ---- epilogue: C/D layout col = lane&15, row = (lane>>4)*4 + r ----
  const int crow0 = m0 + wm * 128;
  const int ccol0 = n0 + wn * 64;
#pragma unroll
  for (int mi = 0; mi < 8; ++mi) {
#pragma unroll
    for (int nj = 0; nj < 4; ++nj) {
      int row = crow0 + mi * 16 + (lk << 2);
      int col = ccol0 + nj * 16 + lr;
      float bc = bias[col];
#pragma unroll
      for (int r = 0; r < 4; ++r) {
        float v = acc[mi][nj][r] + bc;
        size_t idx = (size_t)(row + r) * NDIM + col;
        if (MODE == 0) {
          O[idx] = f2bf(fmaxf(v, 0.f));
        } else if (MODE == 1) {
          O[idx] = f2bf(1.f / (1.f + __expf(-v)));
        } else if (MODE == 2) {
          O[idx] = f2bf(v);
        } else {
          O[idx] = f2bf(v * bf2f(G[idx]) + bf2f(S[idx]));
        }
      }
    }
  }
#undef QUAD
}

// -------- LayerNorm: bf16 rows in, fp32 out (proven r5) --------
__global__ __launch_bounds__(256) void layernorm_bf(
    const unsigned short* __restrict__ Ybf, float* __restrict__ Out,
    const float* __restrict__ gamma, const float* __restrict__ beta) {
  const int tid = threadIdx.x;
  const unsigned short* y = Ybf + (size_t)blockIdx.x * NDIM;
  ushort4 u = reinterpret_cast<const ushort4*>(y)[tid];
  float v0 = bf2f(u.x), v1 = bf2f(u.y), v2 = bf2f(u.z), v3 = bf2f(u.w);
  float s1 = v0 + v1 + v2 + v3;
  float s2 = v0 * v0 + v1 * v1 + v2 * v2 + v3 * v3;
#pragma unroll
  for (int o = 32; o > 0; o >>= 1) {
    s1 += __shfl_down(s1, o, 64);
    s2 += __shfl_down(s2, o, 64);
  }
  __shared__ float red[8];
  int wave = tid >> 6, lane = tid & 63;
  if (lane == 0) { red[wave] = s1; red[wave + 4] = s2; }
  __syncthreads();
  float S1 = red[0] + red[1] + red[2] + red[3];
  float S2 = red[4] + red[5] + red[6] + red[7];
  float mu = S1 * (1.f / NDIM);
  float var = S2 * (1.f / NDIM) - mu * mu;
  float inv = rsqrtf(var + 1e-3f);
  float4 gm = reinterpret_cast<const float4*>(gamma)[tid];
  float4 bt = reinterpret_cast<const float4*>(beta)[tid];
  float4 o;
  o.x = (v0 - mu) * inv * gm.x + bt.x;
  o.y = (v1 - mu) * inv * gm.y + bt.y;
  o.z = (v2 - mu) * inv * gm.z + bt.z;
  o.w = (v3 - mu) * inv * gm.w + bt.w;
  reinterpret_cast<float4*>(Out + (size_t)blockIdx.x * NDIM)[tid] = o;
}

extern "C" void kernel_launch(void* const* d_in, const int* in_sizes, int n_in,
                              void* d_out, int out_size, void* d_ws, size_t ws_size,
                              hipStream_t stream) {
  const float* inp = (const float*)d_in[0];
  const float* w1 = (const float*)d_in[1];
  const float* b1 = (const float*)d_in[2];
  const float* w2 = (const float*)d_in[3];
  const float* b2 = (const float*)d_in[4];
  const float* wg = (const float*)d_in[5];
  const float* bg = (const float*)d_in[6];
  const float* wsk = (const float*)d_in[7];
  const float* bs = (const float*)d_in[8];
  const float* gamma = (const float*)d_in[9];
  const float* beta = (const float*)d_in[10];

  char* p = (char*)d_ws;
  const size_t act_bf16 = (size_t)M_TOT * NDIM * 2;
  const size_t w_bf16 = (size_t)NDIM * NDIM * 2;
  unsigned short* Ain = (unsigned short*)p; p += act_bf16;
  unsigned short* H   = (unsigned short*)p; p += act_bf16;
  unsigned short* G   = (unsigned short*)p; p += act_bf16;
  unsigned short* S   = (unsigned short*)p; p += act_bf16;
  unsigned short* Ybf = (unsigned short*)p; p += act_bf16;
  unsigned short* W1t = (unsigned short*)p; p += w_bf16;
  unsigned short* W2t = (unsigned short*)p; p += w_bf16;
  unsigned short* Wgt = (unsigned short*)p; p += w_bf16;
  unsigned short* Wst = (unsigned short*)p; p += w_bf16;

  cast_in<<<(M_TOT * NDIM / 4 + 255) / 256, 256, 0, stream>>>(inp, Ain, M_TOT * NDIM / 4);
  tcast4<<<dim3(32, 32, 4), 256, 0, stream>>>(w1, w2, wg, wsk, W1t, W2t, Wgt, Wst);

  const int nblk = (M_TOT / 256) * (NDIM / 256);  // 64*4 = 256
  gemm8p<0><<<nblk, 512, 0, stream>>>(Ain, W1t, b1, H, nullptr, nullptr);
  gemm8p<1><<<nblk, 512, 0, stream>>>(Ain, Wgt, bg, G, nullptr, nullptr);
  gemm8p<2><<<nblk, 512, 0, stream>>>(Ain, Wst, bs, S, nullptr, nullptr);
  gemm8p<3><<<nblk, 512, 0, stream>>>(H, W2t, b2, Ybf, G, S);
  layernorm_bf<<<M_TOT, 256, 0, stream>>>(Ybf, (float*)d_out, gamma, beta);
}

// Round 12
// 191.675 us; speedup vs baseline: 1.2235x; 1.1420x over previous
//
#include <hip/hip_runtime.h>
#include <hip/hip_bf16.h>

typedef short short8 __attribute__((ext_vector_type(8)));
typedef float f32x4 __attribute__((ext_vector_type(4)));

#define M_TOT 16384   // B*S = 4*4096
#define NDIM  1024    // D = U = 1024
#define BK 32
#define NT (NDIM / BK)   // 32 K-tiles

static __device__ __forceinline__ unsigned short f2bf(float f) {
  unsigned int u = __builtin_bit_cast(unsigned int, f);
  unsigned int r = (u + 0x7fffu + ((u >> 16) & 1u)) >> 16;   // RN-even
  return (unsigned short)r;
}
static __device__ __forceinline__ float bf2f(unsigned short u) {
  return __builtin_bit_cast(float, ((unsigned int)u) << 16);
}

// compile-time-only reorder fence (zero runtime cost)
#define CLB() asm volatile("" ::: "memory")
#define VMW(N) asm volatile("s_waitcnt vmcnt(" #N ")" ::: "memory")
#define BAR() do { CLB(); __builtin_amdgcn_s_barrier(); CLB(); } while (0)

// ---------------- cast inputs fp32 -> bf16, vectorized ----------------
__global__ __launch_bounds__(256) void cast_in(const float* __restrict__ in,
                                               unsigned short* __restrict__ out,
                                               int n4) {
  int i = blockIdx.x * 256 + threadIdx.x;
  if (i >= n4) return;
  float4 v = reinterpret_cast<const float4*>(in)[i];
  ushort4 o;
  o.x = f2bf(v.x); o.y = f2bf(v.y); o.z = f2bf(v.z); o.w = f2bf(v.w);
  reinterpret_cast<ushort4*>(out)[i] = o;
}

// ---- transpose-cast 4 weights fp32 [K][N] -> bf16 [N][K], one launch ----
__global__ __launch_bounds__(256) void tcast4(
    const float* __restrict__ w1, const float* __restrict__ w2,
    const float* __restrict__ wg, const float* __restrict__ ws,
    unsigned short* __restrict__ W1t, unsigned short* __restrict__ W2t,
    unsigned short* __restrict__ Wgt, unsigned short* __restrict__ Wst) {
  const int z = blockIdx.z;
  const float* src = (z == 0) ? w1 : (z == 1) ? w2 : (z == 2) ? wg : ws;
  unsigned short* dst = (z == 0) ? W1t : (z == 1) ? W2t : (z == 2) ? Wgt : Wst;
  __shared__ unsigned short tile[32][33];
  int bx = blockIdx.x * 32, by = blockIdx.y * 32;
  int x = threadIdx.x & 31, y = threadIdx.x >> 5;  // 32 x 8
#pragma unroll
  for (int i = 0; i < 32; i += 8)
    tile[y + i][x] = f2bf(src[(size_t)(by + y + i) * NDIM + bx + x]);
  __syncthreads();
#pragma unroll
  for (int i = 0; i < 32; i += 8)
    dst[(size_t)(bx + y + i) * NDIM + by + x] = tile[x][y + i];
}

// ========== tri-GEMM: 256x128 tile, 8 waves, stage A once (r9 best) ==========
// H = bf16(relu(x@W1+b1)); G = bf16(sigmoid(x@Wg+bg)); S = bf16(x@Ws+bs)
__global__ __launch_bounds__(512, 2) void trigemm(
    const unsigned short* __restrict__ A,
    const unsigned short* __restrict__ W1t,
    const unsigned short* __restrict__ Wgt,
    const unsigned short* __restrict__ Wst,
    const float* __restrict__ b1,
    const float* __restrict__ bg,
    const float* __restrict__ bs,
    unsigned short* __restrict__ H,
    unsigned short* __restrict__ G,
    unsigned short* __restrict__ S) {
  // per buf: shorts 0..8191 = A (row-major 256x32), 8192 + w*4096 + row*32 = W_w
  __shared__ __align__(16) unsigned short lds[2][20480];  // 80 KB

  const int tid = threadIdx.x;
  const int lane = tid & 63;
  const int wave = tid >> 6;            // 0..7
  const int wm = wave >> 1;             // 0..3  (64-row band)
  const int wn = wave & 1;              // 0..1  (64-col half)
  const int lr = lane & 15;
  const int lk = lane >> 4;

  // XCD swizzle: 8 col-blocks sharing an A row-panel -> same XCD.
  const int id = blockIdx.x;
  const int xcd = id & 7;
  const int slot = id >> 3;                // 0..63
  const int rblk = xcd + 8 * (slot >> 3);  // 0..63
  const int cblk = slot & 7;               // 0..7
  const int m0 = rblk * 256, n0 = cblk * 128;

  const unsigned short* gA = A + (size_t)m0 * NDIM;
  const unsigned short* gW[3] = {W1t + (size_t)n0 * NDIM, Wgt + (size_t)n0 * NDIM,
                                 Wst + (size_t)n0 * NDIM};

  f32x4 acc[3][4][4] = {};

  // stage K-tile kt: A 1024 chunks + 3x512 W chunks = 2560 / 512thr = 5 each
  auto stage = [&](int buf, int kt) {
#pragma unroll
    for (int q = 0; q < 5; ++q) {
      int cid = q * 512 + tid;             // 0..2559
      const unsigned short* g;
      if (q < 2) {                          // A chunks 0..1023
        int row = cid >> 2;                 // 0..255
        int c = (cid & 3) ^ ((row >> 1) & 3);
        g = gA + (size_t)row * NDIM + kt * BK + c * 8;
      } else {                              // W chunks, mat = q-2 (compile-time)
        int local = cid - 1024;
        int w = q - 2;
        int lrow = local & 511;
        int row = lrow >> 2;                // 0..127
        int c = (lrow & 3) ^ ((row >> 1) & 3);
        g = gW[w] + (size_t)row * NDIM + kt * BK + c * 8;
      }
      unsigned short* l = &lds[buf][0] + (size_t)(q * 512 + (tid & ~63)) * 8;
      __builtin_amdgcn_global_load_lds(
          (__attribute__((address_space(1))) void*)g,
          (__attribute__((address_space(3))) void*)l, 16, 0, 0);
    }
  };

  auto compute = [&](int buf) {
    short8 af[4];
#pragma unroll
    for (int mi = 0; mi < 4; ++mi) {
      int row = wm * 64 + mi * 16 + lr;
      int cs = lk ^ ((row >> 1) & 3);
      af[mi] = *reinterpret_cast<const short8*>(&lds[buf][row * 32 + cs * 8]);
    }
#pragma unroll
    for (int w = 0; w < 3; ++w) {
      short8 bf[4];
#pragma unroll
      for (int nj = 0; nj < 4; ++nj) {
        int row = wn * 64 + nj * 16 + lr;
        int cs = lk ^ ((row >> 1) & 3);
        bf[nj] = *reinterpret_cast<const short8*>(
            &lds[buf][8192 + w * 4096 + row * 32 + cs * 8]);
      }
      __builtin_amdgcn_s_setprio(1);
#pragma unroll
      for (int mi = 0; mi < 4; ++mi)
#pragma unroll
        for (int nj = 0; nj < 4; ++nj)
          acc[w][mi][nj] = __builtin_amdgcn_mfma_f32_16x16x32_bf16(
              af[mi], bf[nj], acc[w][mi][nj], 0, 0, 0);
      __builtin_amdgcn_s_setprio(0);
    }
  };

  stage(0, 0);
  for (int t = 0; t < NT; ++t) {
    const int cur = t & 1;
    if (t + 1 < NT) {
      stage(cur ^ 1, t + 1);   // 5 new in flight, then wait current 5
      VMW(5);
    } else {
      VMW(0);
    }
    BAR();
    compute(cur);
    BAR();
  }

  // epilogue: C/D layout col = lane&15, row = (lane>>4)*4 + r
  const int crow0 = m0 + wm * 64;
  const int ccol0 = n0 + wn * 64;
#pragma unroll
  for (int w = 0; w < 3; ++w) {
    const float* bptr = (w == 0) ? b1 : (w == 1) ? bg : bs;
    unsigned short* optr = (w == 0) ? H : (w == 1) ? G : S;
#pragma unroll
    for (int mi = 0; mi < 4; ++mi) {
#pragma unroll
      for (int nj = 0; nj < 4; ++nj) {
        int row = crow0 + mi * 16 + (lk << 2);
        int col = ccol0 + nj * 16 + lr;
        float bc = bptr[col];
#pragma unroll
        for (int r = 0; r < 4; ++r) {
          float v = acc[w][mi][nj][r] + bc;
          if (w == 0) v = fmaxf(v, 0.f);
          else if (w == 1) v = 1.f / (1.f + __expf(-v));
          optr[(size_t)(row + r) * NDIM + col] = f2bf(v);
        }
      }
    }
  }
}

// ========== y-GEMM: 256x128 tile, trigemm-structure, 48 KB LDS ==========
// O = bf16((H@W2t^T + b2) * G + S)
// 8 waves (4 wm x 2 wn), 64x64/wave, acc[4][4]=64 VGPR.  LDS per buf:
// A 256x32 (16KB) + B 128x32 (8KB) = 24KB; x2 = 48KB -> 2-3 blocks/CU
// (desync overlap, the configuration that empirically lifted MfmaUtil).
// 3 loads/thread/tile -> counted VMW(3); same proven swizzle + 2-barrier loop.
__global__ __launch_bounds__(512, 2) void gemm_y(
    const unsigned short* __restrict__ A,
    const unsigned short* __restrict__ Bt,
    const float* __restrict__ bias,
    unsigned short* __restrict__ O,
    const unsigned short* __restrict__ G,
    const unsigned short* __restrict__ S) {
  // per buf: shorts 0..8191 = A (256x32), 8192 + row*32 = B (128x32)
  __shared__ __align__(16) unsigned short lds[2][12288];  // 48 KB

  const int tid = threadIdx.x;
  const int lane = tid & 63;
  const int wave = tid >> 6;            // 0..7
  const int wm = wave >> 1;             // 0..3  (64-row band)
  const int wn = wave & 1;              // 0..1  (64-col half)
  const int lr = lane & 15;
  const int lk = lane >> 4;

  // XCD swizzle: 8 col-blocks per A row-panel -> same XCD (512 blocks)
  const int id = blockIdx.x;
  const int xcd = id & 7;
  const int slot = id >> 3;                // 0..63
  const int rblk = xcd + 8 * (slot >> 3);  // 0..63
  const int cblk = slot & 7;               // 0..7
  const int m0 = rblk * 256, n0 = cblk * 128;

  const unsigned short* gA = A + (size_t)m0 * NDIM;
  const unsigned short* gB = Bt + (size_t)n0 * NDIM;

  f32x4 acc[4][4] = {};

  // stage K-tile kt: A 1024 + B 512 chunks = 1536 / 512thr = 3 each
  auto stage = [&](int buf, int kt) {
#pragma unroll
    for (int q = 0; q < 3; ++q) {
      int cid = q * 512 + tid;             // 0..1535
      const unsigned short* g;
      if (q < 2) {                          // A chunks 0..1023
        int row = cid >> 2;                 // 0..255
        int c = (cid & 3) ^ ((row >> 1) & 3);
        g = gA + (size_t)row * NDIM + kt * BK + c * 8;
      } else {                              // B chunks 0..511
        int local = cid - 1024;
        int row = local >> 2;               // 0..127
        int c = (local & 3) ^ ((row >> 1) & 3);
        g = gB + (size_t)row * NDIM + kt * BK + c * 8;
      }
      unsigned short* l = &lds[buf][0] + (size_t)(q * 512 + (tid & ~63)) * 8;
      __builtin_amdgcn_global_load_lds(
          (__attribute__((address_space(1))) void*)g,
          (__attribute__((address_space(3))) void*)l, 16, 0, 0);
    }
  };

  auto compute = [&](int buf) {
    short8 af[4], bf[4];
#pragma unroll
    for (int mi = 0; mi < 4; ++mi) {
      int row = wm * 64 + mi * 16 + lr;
      int cs = lk ^ ((row >> 1) & 3);
      af[mi] = *reinterpret_cast<const short8*>(&lds[buf][row * 32 + cs * 8]);
    }
#pragma unroll
    for (int nj = 0; nj < 4; ++nj) {
      int row = wn * 64 + nj * 16 + lr;
      int cs = lk ^ ((row >> 1) & 3);
      bf[nj] = *reinterpret_cast<const short8*>(&lds[buf][8192 + row * 32 + cs * 8]);
    }
    __builtin_amdgcn_s_setprio(1);
#pragma unroll
    for (int mi = 0; mi < 4; ++mi)
#pragma unroll
      for (int nj = 0; nj < 4; ++nj)
        acc[mi][nj] = __builtin_amdgcn_mfma_f32_16x16x32_bf16(
            af[mi], bf[nj], acc[mi][nj], 0, 0, 0);
    __builtin_amdgcn_s_setprio(0);
  };

  stage(0, 0);
  for (int t = 0; t < NT; ++t) {
    const int cur = t & 1;
    if (t + 1 < NT) {
      stage(cur ^ 1, t + 1);
      VMW(3);
    } else {
      VMW(0);
    }
    BAR();
    compute(cur);
    BAR();
  }

  // epilogue: gate + skip, write bf16 Ybf
  const int crow0 = m0 + wm * 64;
  const int ccol0 = n0 + wn * 64;
#pragma unroll
  for (int mi = 0; mi < 4; ++mi) {
#pragma unroll
    for (int nj = 0; nj < 4; ++nj) {
      int row = crow0 + mi * 16 + (lk << 2);
      int col = ccol0 + nj * 16 + lr;
      float bc = bias[col];
#pragma unroll
      for (int r = 0; r < 4; ++r) {
        float v = acc[mi][nj][r] + bc;
        size_t idx = (size_t)(row + r) * NDIM + col;
        O[idx] = f2bf(v * bf2f(G[idx]) + bf2f(S[idx]));
      }
    }
  }
}

// -------- LayerNorm: bf16 rows in, fp32 out (proven r5) --------
__global__ __launch_bounds__(256) void layernorm_bf(
    const unsigned short* __restrict__ Ybf, float* __restrict__ Out,
    const float* __restrict__ gamma, const float* __restrict__ beta) {
  const int tid = threadIdx.x;
  const unsigned short* y = Ybf + (size_t)blockIdx.x * NDIM;
  ushort4 u = reinterpret_cast<const ushort4*>(y)[tid];
  float v0 = bf2f(u.x), v1 = bf2f(u.y), v2 = bf2f(u.z), v3 = bf2f(u.w);
  float s1 = v0 + v1 + v2 + v3;
  float s2 = v0 * v0 + v1 * v1 + v2 * v2 + v3 * v3;
#pragma unroll
  for (int o = 32; o > 0; o >>= 1) {
    s1 += __shfl_down(s1, o, 64);
    s2 += __shfl_down(s2, o, 64);
  }
  __shared__ float red[8];
  int wave = tid >> 6, lane = tid & 63;
  if (lane == 0) { red[wave] = s1; red[wave + 4] = s2; }
  __syncthreads();
  float S1 = red[0] + red[1] + red[2] + red[3];
  float S2 = red[4] + red[5] + red[6] + red[7];
  float mu = S1 * (1.f / NDIM);
  float var = S2 * (1.f / NDIM) - mu * mu;
  float inv = rsqrtf(var + 1e-3f);
  float4 gm = reinterpret_cast<const float4*>(gamma)[tid];
  float4 bt = reinterpret_cast<const float4*>(beta)[tid];
  float4 o;
  o.x = (v0 - mu) * inv * gm.x + bt.x;
  o.y = (v1 - mu) * inv * gm.y + bt.y;
  o.z = (v2 - mu) * inv * gm.z + bt.z;
  o.w = (v3 - mu) * inv * gm.w + bt.w;
  reinterpret_cast<float4*>(Out + (size_t)blockIdx.x * NDIM)[tid] = o;
}

extern "C" void kernel_launch(void* const* d_in, const int* in_sizes, int n_in,
                              void* d_out, int out_size, void* d_ws, size_t ws_size,
                              hipStream_t stream) {
  const float* inp = (const float*)d_in[0];
  const float* w1 = (const float*)d_in[1];
  const float* b1 = (const float*)d_in[2];
  const float* w2 = (const float*)d_in[3];
  const float* b2 = (const float*)d_in[4];
  const float* wg = (const float*)d_in[5];
  const float* bg = (const float*)d_in[6];
  const float* wsk = (const float*)d_in[7];
  const float* bs = (const float*)d_in[8];
  const float* gamma = (const float*)d_in[9];
  const float* beta = (const float*)d_in[10];

  char* p = (char*)d_ws;
  const size_t act_bf16 = (size_t)M_TOT * NDIM * 2;
  const size_t w_bf16 = (size_t)NDIM * NDIM * 2;
  unsigned short* Ain = (unsigned short*)p; p += act_bf16;
  unsigned short* H   = (unsigned short*)p; p += act_bf16;
  unsigned short* G   = (unsigned short*)p; p += act_bf16;
  unsigned short* S   = (unsigned short*)p; p += act_bf16;
  unsigned short* Ybf = (unsigned short*)p; p += act_bf16;
  unsigned short* W1t = (unsigned short*)p; p += w_bf16;
  unsigned short* W2t = (unsigned short*)p; p += w_bf16;
  unsigned short* Wgt = (unsigned short*)p; p += w_bf16;
  unsigned short* Wst = (unsigned short*)p; p += w_bf16;

  cast_in<<<(M_TOT * NDIM / 4 + 255) / 256, 256, 0, stream>>>(inp, Ain, M_TOT * NDIM / 4);
  tcast4<<<dim3(32, 32, 4), 256, 0, stream>>>(w1, w2, wg, wsk, W1t, W2t, Wgt, Wst);

  trigemm<<<(M_TOT / 256) * (NDIM / 128), 512, 0, stream>>>(
      Ain, W1t, Wgt, Wst, b1, bg, bs, H, G, S);
  gemm_y<<<(M_TOT / 256) * (NDIM / 128), 512, 0, stream>>>(H, W2t, b2, Ybf, G, S);
  layernorm_bf<<<M_TOT, 256, 0, stream>>>(Ybf, (float*)d_out, gamma, beta);
}

// Round 13
// 189.184 us; speedup vs baseline: 1.2396x; 1.0132x over previous
//
#include <hip/hip_runtime.h>
#include <hip/hip_bf16.h>

typedef short short8 __attribute__((ext_vector_type(8)));
typedef float f32x4 __attribute__((ext_vector_type(4)));

#define M_TOT 16384   // B*S = 4*4096
#define NDIM  1024    // D = U = 1024
#define BK 32
#define NT (NDIM / BK)   // 32 K-tiles

static __device__ __forceinline__ unsigned short f2bf(float f) {
  unsigned int u = __builtin_bit_cast(unsigned int, f);
  unsigned int r = (u + 0x7fffu + ((u >> 16) & 1u)) >> 16;   // RN-even
  return (unsigned short)r;
}
static __device__ __forceinline__ float bf2f(unsigned short u) {
  return __builtin_bit_cast(float, ((unsigned int)u) << 16);
}

// compile-time-only reorder fence (zero runtime cost)
#define CLB() asm volatile("" ::: "memory")
#define VMW(N) asm volatile("s_waitcnt vmcnt(" #N ")" ::: "memory")
#define BAR() do { CLB(); __builtin_amdgcn_s_barrier(); CLB(); } while (0)

// ---------------- cast inputs fp32 -> bf16, vectorized ----------------
__global__ __launch_bounds__(256) void cast_in(const float* __restrict__ in,
                                               unsigned short* __restrict__ out,
                                               int n4) {
  int i = blockIdx.x * 256 + threadIdx.x;
  if (i >= n4) return;
  float4 v = reinterpret_cast<const float4*>(in)[i];
  ushort4 o;
  o.x = f2bf(v.x); o.y = f2bf(v.y); o.z = f2bf(v.z); o.w = f2bf(v.w);
  reinterpret_cast<ushort4*>(out)[i] = o;
}

// ---- transpose-cast 4 weights fp32 [K][N] -> bf16 [N][K], one launch ----
__global__ __launch_bounds__(256) void tcast4(
    const float* __restrict__ w1, const float* __restrict__ w2,
    const float* __restrict__ wg, const float* __restrict__ ws,
    unsigned short* __restrict__ W1t, unsigned short* __restrict__ W2t,
    unsigned short* __restrict__ Wgt, unsigned short* __restrict__ Wst) {
  const int z = blockIdx.z;
  const float* src = (z == 0) ? w1 : (z == 1) ? w2 : (z == 2) ? wg : ws;
  unsigned short* dst = (z == 0) ? W1t : (z == 1) ? W2t : (z == 2) ? Wgt : Wst;
  __shared__ unsigned short tile[32][33];
  int bx = blockIdx.x * 32, by = blockIdx.y * 32;
  int x = threadIdx.x & 31, y = threadIdx.x >> 5;  // 32 x 8
#pragma unroll
  for (int i = 0; i < 32; i += 8)
    tile[y + i][x] = f2bf(src[(size_t)(by + y + i) * NDIM + bx + x]);
  __syncthreads();
#pragma unroll
  for (int i = 0; i < 32; i += 8)
    dst[(size_t)(bx + y + i) * NDIM + by + x] = tile[x][y + i];
}

// ========== tri-GEMM: 256x128 tile, 8 waves (2x4), stage A once ==========
// H = bf16(relu(x@W1+b1)); G = bf16(sigmoid(x@Wg+bg)); S = bf16(x@Ws+bs)
// Wave = 128 rows x 32 cols per weight (2x4 split): LDS reads/wave/tile =
// A 8 + B 2x3 = 14 b128 (vs 16 for 4x2) — B is the 3x-replicated operand,
// so shrinking per-wave B-cols cuts total block LDS reads 12.5%.
// Single barrier per K-tile (T3-minimum): stage(next) -> compute(cur) ->
// vmcnt(0) -> barrier.  Hazards: iter t-1 reads buf B' complete (in regs)
// before each wave's own barrier arrival; iter t's stage writes B' only
// after that barrier; gload_lds within iter t writes B' while reads hit B.
__global__ __launch_bounds__(512, 2) void trigemm(
    const unsigned short* __restrict__ A,
    const unsigned short* __restrict__ W1t,
    const unsigned short* __restrict__ Wgt,
    const unsigned short* __restrict__ Wst,
    const float* __restrict__ b1,
    const float* __restrict__ bg,
    const float* __restrict__ bs,
    unsigned short* __restrict__ H,
    unsigned short* __restrict__ G,
    unsigned short* __restrict__ S) {
  // per buf: shorts 0..8191 = A (row-major 256x32), 8192 + w*4096 + row*32 = W_w
  __shared__ __align__(16) unsigned short lds[2][20480];  // 80 KB -> 2 blocks/CU

  const int tid = threadIdx.x;
  const int lane = tid & 63;
  const int wave = tid >> 6;            // 0..7
  const int wm = wave >> 2;             // 0..1  (128-row band)
  const int wn = wave & 3;              // 0..3  (32-col slice)
  const int lr = lane & 15;
  const int lk = lane >> 4;

  // XCD swizzle: 8 col-blocks sharing an A row-panel -> same XCD.
  const int id = blockIdx.x;
  const int xcd = id & 7;
  const int slot = id >> 3;                // 0..63
  const int rblk = xcd + 8 * (slot >> 3);  // 0..63
  const int cblk = slot & 7;               // 0..7
  const int m0 = rblk * 256, n0 = cblk * 128;

  const unsigned short* gA = A + (size_t)m0 * NDIM;
  const unsigned short* gW[3] = {W1t + (size_t)n0 * NDIM, Wgt + (size_t)n0 * NDIM,
                                 Wst + (size_t)n0 * NDIM};

  f32x4 acc[3][8][2] = {};

  // stage K-tile kt: A 1024 chunks + 3x512 W chunks = 2560 / 512thr = 5 each
  auto stage = [&](int buf, int kt) {
#pragma unroll
    for (int q = 0; q < 5; ++q) {
      int cid = q * 512 + tid;             // 0..2559
      const unsigned short* g;
      if (q < 2) {                          // A chunks 0..1023
        int row = cid >> 2;                 // 0..255
        int c = (cid & 3) ^ ((row >> 1) & 3);
        g = gA + (size_t)row * NDIM + kt * BK + c * 8;
      } else {                              // W chunks, mat = q-2 (compile-time)
        int local = cid - 1024;
        int w = q - 2;
        int lrow = local & 511;
        int row = lrow >> 2;                // 0..127
        int c = (lrow & 3) ^ ((row >> 1) & 3);
        g = gW[w] + (size_t)row * NDIM + kt * BK + c * 8;
      }
      unsigned short* l = &lds[buf][0] + (size_t)(q * 512 + (tid & ~63)) * 8;
      __builtin_amdgcn_global_load_lds(
          (__attribute__((address_space(1))) void*)g,
          (__attribute__((address_space(3))) void*)l, 16, 0, 0);
    }
  };

  auto compute = [&](int buf) {
    short8 af[8];
#pragma unroll
    for (int mi = 0; mi < 8; ++mi) {
      int row = wm * 128 + mi * 16 + lr;
      int cs = lk ^ ((row >> 1) & 3);
      af[mi] = *reinterpret_cast<const short8*>(&lds[buf][row * 32 + cs * 8]);
    }
#pragma unroll
    for (int w = 0; w < 3; ++w) {
      short8 bf[2];
#pragma unroll
      for (int nj = 0; nj < 2; ++nj) {
        int row = wn * 32 + nj * 16 + lr;
        int cs = lk ^ ((row >> 1) & 3);
        bf[nj] = *reinterpret_cast<const short8*>(
            &lds[buf][8192 + w * 4096 + row * 32 + cs * 8]);
      }
      __builtin_amdgcn_s_setprio(1);
#pragma unroll
      for (int mi = 0; mi < 8; ++mi)
#pragma unroll
        for (int nj = 0; nj < 2; ++nj)
          acc[w][mi][nj] = __builtin_amdgcn_mfma_f32_16x16x32_bf16(
              af[mi], bf[nj], acc[w][mi][nj], 0, 0, 0);
      __builtin_amdgcn_s_setprio(0);
    }
  };

  // prologue: tile 0 staged and landed
  stage(0, 0);
  VMW(0);
  BAR();
  for (int t = 0; t < NT; ++t) {
    const int cur = t & 1;
    if (t + 1 < NT) stage(cur ^ 1, t + 1);  // issue early, land under compute
    compute(cur);
    VMW(0);                                 // own next-tile loads landed
    BAR();                                  // single barrier per tile
  }

  // epilogue: C/D layout col = lane&15, row = (lane>>4)*4 + r
  const int crow0 = m0 + wm * 128;
  const int ccol0 = n0 + wn * 32;
#pragma unroll
  for (int w = 0; w < 3; ++w) {
    const float* bptr = (w == 0) ? b1 : (w == 1) ? bg : bs;
    unsigned short* optr = (w == 0) ? H : (w == 1) ? G : S;
#pragma unroll
    for (int mi = 0; mi < 8; ++mi) {
#pragma unroll
      for (int nj = 0; nj < 2; ++nj) {
        int row = crow0 + mi * 16 + (lk << 2);
        int col = ccol0 + nj * 16 + lr;
        float bc = bptr[col];
#pragma unroll
        for (int r = 0; r < 4; ++r) {
          float v = acc[w][mi][nj][r] + bc;
          if (w == 0) v = fmaxf(v, 0.f);
          else if (w == 1) v = 1.f / (1.f + __expf(-v));
          optr[(size_t)(row + r) * NDIM + col] = f2bf(v);
        }
      }
    }
  }
}

// ========== y-GEMM: 256x128 tile, 8 waves (2x4), 48 KB LDS ==========
// O = bf16((H@W2t^T + b2) * G + S)
__global__ __launch_bounds__(512, 2) void gemm_y(
    const unsigned short* __restrict__ A,
    const unsigned short* __restrict__ Bt,
    const float* __restrict__ bias,
    unsigned short* __restrict__ O,
    const unsigned short* __restrict__ G,
    const unsigned short* __restrict__ S) {
  // per buf: shorts 0..8191 = A (256x32), 8192 + row*32 = B (128x32)
  __shared__ __align__(16) unsigned short lds[2][12288];  // 48 KB

  const int tid = threadIdx.x;
  const int lane = tid & 63;
  const int wave = tid >> 6;            // 0..7
  const int wm = wave >> 2;             // 0..1  (128-row band)
  const int wn = wave & 3;              // 0..3  (32-col slice)
  const int lr = lane & 15;
  const int lk = lane >> 4;

  // XCD swizzle: 8 col-blocks per A row-panel -> same XCD (512 blocks)
  const int id = blockIdx.x;
  const int xcd = id & 7;
  const int slot = id >> 3;                // 0..63
  const int rblk = xcd + 8 * (slot >> 3);  // 0..63
  const int cblk = slot & 7;               // 0..7
  const int m0 = rblk * 256, n0 = cblk * 128;

  const unsigned short* gA = A + (size_t)m0 * NDIM;
  const unsigned short* gB = Bt + (size_t)n0 * NDIM;

  f32x4 acc[8][2] = {};

  // stage K-tile kt: A 1024 + B 512 chunks = 1536 / 512thr = 3 each
  auto stage = [&](int buf, int kt) {
#pragma unroll
    for (int q = 0; q < 3; ++q) {
      int cid = q * 512 + tid;             // 0..1535
      const unsigned short* g;
      if (q < 2) {                          // A chunks 0..1023
        int row = cid >> 2;                 // 0..255
        int c = (cid & 3) ^ ((row >> 1) & 3);
        g = gA + (size_t)row * NDIM + kt * BK + c * 8;
      } else {                              // B chunks 0..511
        int local = cid - 1024;
        int row = local >> 2;               // 0..127
        int c = (local & 3) ^ ((row >> 1) & 3);
        g = gB + (size_t)row * NDIM + kt * BK + c * 8;
      }
      unsigned short* l = &lds[buf][0] + (size_t)(q * 512 + (tid & ~63)) * 8;
      __builtin_amdgcn_global_load_lds(
          (__attribute__((address_space(1))) void*)g,
          (__attribute__((address_space(3))) void*)l, 16, 0, 0);
    }
  };

  auto compute = [&](int buf) {
    short8 af[8], bf[2];
#pragma unroll
    for (int mi = 0; mi < 8; ++mi) {
      int row = wm * 128 + mi * 16 + lr;
      int cs = lk ^ ((row >> 1) & 3);
      af[mi] = *reinterpret_cast<const short8*>(&lds[buf][row * 32 + cs * 8]);
    }
#pragma unroll
    for (int nj = 0; nj < 2; ++nj) {
      int row = wn * 32 + nj * 16 + lr;
      int cs = lk ^ ((row >> 1) & 3);
      bf[nj] = *reinterpret_cast<const short8*>(&lds[buf][8192 + row * 32 + cs * 8]);
    }
    __builtin_amdgcn_s_setprio(1);
#pragma unroll
    for (int mi = 0; mi < 8; ++mi)
#pragma unroll
      for (int nj = 0; nj < 2; ++nj)
        acc[mi][nj] = __builtin_amdgcn_mfma_f32_16x16x32_bf16(
            af[mi], bf[nj], acc[mi][nj], 0, 0, 0);
    __builtin_amdgcn_s_setprio(0);
  };

  stage(0, 0);
  VMW(0);
  BAR();
  for (int t = 0; t < NT; ++t) {
    const int cur = t & 1;
    if (t + 1 < NT) stage(cur ^ 1, t + 1);
    compute(cur);
    VMW(0);
    BAR();
  }

  // epilogue: gate + skip, write bf16 Ybf
  const int crow0 = m0 + wm * 128;
  const int ccol0 = n0 + wn * 32;
#pragma unroll
  for (int mi = 0; mi < 8; ++mi) {
#pragma unroll
    for (int nj = 0; nj < 2; ++nj) {
      int row = crow0 + mi * 16 + (lk << 2);
      int col = ccol0 + nj * 16 + lr;
      float bc = bias[col];
#pragma unroll
      for (int r = 0; r < 4; ++r) {
        float v = acc[mi][nj][r] + bc;
        size_t idx = (size_t)(row + r) * NDIM + col;
        O[idx] = f2bf(v * bf2f(G[idx]) + bf2f(S[idx]));
      }
    }
  }
}

// -------- LayerNorm: bf16 rows in, fp32 out (proven r5) --------
__global__ __launch_bounds__(256) void layernorm_bf(
    const unsigned short* __restrict__ Ybf, float* __restrict__ Out,
    const float* __restrict__ gamma, const float* __restrict__ beta) {
  const int tid = threadIdx.x;
  const unsigned short* y = Ybf + (size_t)blockIdx.x * NDIM;
  ushort4 u = reinterpret_cast<const ushort4*>(y)[tid];
  float v0 = bf2f(u.x), v1 = bf2f(u.y), v2 = bf2f(u.z), v3 = bf2f(u.w);
  float s1 = v0 + v1 + v2 + v3;
  float s2 = v0 * v0 + v1 * v1 + v2 * v2 + v3 * v3;
#pragma unroll
  for (int o = 32; o > 0; o >>= 1) {
    s1 += __shfl_down(s1, o, 64);
    s2 += __shfl_down(s2, o, 64);
  }
  __shared__ float red[8];
  int wave = tid >> 6, lane = tid & 63;
  if (lane == 0) { red[wave] = s1; red[wave + 4] = s2; }
  __syncthreads();
  float S1 = red[0] + red[1] + red[2] + red[3];
  float S2 = red[4] + red[5] + red[6] + red[7];
  float mu = S1 * (1.f / NDIM);
  float var = S2 * (1.f / NDIM) - mu * mu;
  float inv = rsqrtf(var + 1e-3f);
  float4 gm = reinterpret_cast<const float4*>(gamma)[tid];
  float4 bt = reinterpret_cast<const float4*>(beta)[tid];
  float4 o;
  o.x = (v0 - mu) * inv * gm.x + bt.x;
  o.y = (v1 - mu) * inv * gm.y + bt.y;
  o.z = (v2 - mu) * inv * gm.z + bt.z;
  o.w = (v3 - mu) * inv * gm.w + bt.w;
  reinterpret_cast<float4*>(Out + (size_t)blockIdx.x * NDIM)[tid] = o;
}

extern "C" void kernel_launch(void* const* d_in, const int* in_sizes, int n_in,
                              void* d_out, int out_size, void* d_ws, size_t ws_size,
                              hipStream_t stream) {
  const float* inp = (const float*)d_in[0];
  const float* w1 = (const float*)d_in[1];
  const float* b1 = (const float*)d_in[2];
  const float* w2 = (const float*)d_in[3];
  const float* b2 = (const float*)d_in[4];
  const float* wg = (const float*)d_in[5];
  const float* bg = (const float*)d_in[6];
  const float* wsk = (const float*)d_in[7];
  const float* bs = (const float*)d_in[8];
  const float* gamma = (const float*)d_in[9];
  const float* beta = (const float*)d_in[10];

  char* p = (char*)d_ws;
  const size_t act_bf16 = (size_t)M_TOT * NDIM * 2;
  const size_t w_bf16 = (size_t)NDIM * NDIM * 2;
  unsigned short* Ain = (unsigned short*)p; p += act_bf16;
  unsigned short* H   = (unsigned short*)p; p += act_bf16;
  unsigned short* G   = (unsigned short*)p; p += act_bf16;
  unsigned short* S   = (unsigned short*)p; p += act_bf16;
  unsigned short* Ybf = (unsigned short*)p; p += act_bf16;
  unsigned short* W1t = (unsigned short*)p; p += w_bf16;
  unsigned short* W2t = (unsigned short*)p; p += w_bf16;
  unsigned short* Wgt = (unsigned short*)p; p += w_bf16;
  unsigned short* Wst = (unsigned short*)p; p += w_bf16;

  cast_in<<<(M_TOT * NDIM / 4 + 255) / 256, 256, 0, stream>>>(inp, Ain, M_TOT * NDIM / 4);
  tcast4<<<dim3(32, 32, 4), 256, 0, stream>>>(w1, w2, wg, wsk, W1t, W2t, Wgt, Wst);

  trigemm<<<(M_TOT / 256) * (NDIM / 128), 512, 0, stream>>>(
      Ain, W1t, Wgt, Wst, b1, bg, bs, H, G, S);
  gemm_y<<<(M_TOT / 256) * (NDIM / 128), 512, 0, stream>>>(H, W2t, b2, Ybf, G, S);
  layernorm_bf<<<M_TOT, 256, 0, stream>>>(Ybf, (float*)d_out, gamma, beta);
}